// Round 1
// 248.926 us; speedup vs baseline: 1.1011x; 1.1011x over previous
//
#include <hip/hip_runtime.h>
#include <math.h>

#define G 8
#define Hd 256
#define Wd 256
#define HW (Hd * Wd)

typedef float fvec4 __attribute__((ext_vector_type(4)));

// ---------------------------------------------------------------------------
// One block (1024 thr = 16 waves) per (b,c) image. Row-ballot GLCM:
// a wave's 64 lanes = 64 consecutive columns, 4 segments cover 256 cols.
// Lane L owns bin L (i = L>>3, j = L&7).
//
// v2 changes vs prior best (272 us):
//  * mjl/mjr are now single shifts of the COMPOSED j-match mask MJ instead of
//    re-running the 3-bitplane XNOR-AND tree on shifted bitplanes:
//      mk_mj(B<<1) == (mk_mj(B)<<1) | carry   (bit-exact, zero-pad bit0 = (j==0))
//  * mi is a lane permutation of MJ: mi[L] = MJ[L>>3] -> one ds_bpermute pair
//    (LDS pipe, off the VALU). cnt0 deferred one row (MJL_prev) so the
//    bpermute result is consumed a row later -> latency off critical path.
//  * next-row loads issued before current-row compute (SW pipeline).
//  * scale pass fused into the tail: wplus is block-local; image re-read hits
//    L3 (just streamed), out written with nontemporal stores. Second kernel
//    and its 268 MB of traffic + launch are gone.
//
// Pair semantics (d=1, angles 0, pi/4, pi/2, 3pi/4), zero-padded borders:
//   angle0: (q(y,x), q(y,x-1))   angle1: (q(y+1... ) as in prior version.
// OOB neighbor -> q=0 -> bin j=0 (shift-in carry JL0/JR0 and MJPAD row).
// ---------------------------------------------------------------------------
__global__ __launch_bounds__(1024) void glcm_fused(const float* __restrict__ x,
                                                   const float* __restrict__ W1,
                                                   const float* __restrict__ W2,
                                                   float* __restrict__ out) {
    __shared__ unsigned int hist[4 * 64];   // [angle][i*8+j]
    __shared__ float feats_s[16];
    __shared__ float h_s[16];
    __shared__ float wplus_s;

    const int t = threadIdx.x;
    const int bc = blockIdx.x;              // b*64 + c
    const float* img = x + (size_t)bc * HW;

    if (t < 256) hist[t] = 0u;

    const int lane = t & 63;
    const int wv = t >> 6;                  // 0..15
    const int r0 = wv << 4;                 // first owned row

    // j-selectors (j = lane&7): XNOR-select composition of ballot bitplanes.
    const unsigned long long F0 = (lane & 1) ? 0ull : ~0ull;
    const unsigned long long F1 = (lane & 2) ? 0ull : ~0ull;
    const unsigned long long F2 = (lane & 4) ? 0ull : ~0ull;
    const unsigned long long MJPAD = F0 & F1 & F2;        // mask of a zero-pad row
    const unsigned long long JL0 = MJPAD & 1ull;          // bit0 after <<1 at s=0
    const unsigned long long JR0 = MJPAD & (1ull << 63);  // bit63 after >>1 at s=3
    const int baddr = (lane >> 3) << 2;     // ds_bpermute byte addr: lane i(L)

    unsigned int cnt0 = 0, cnt1 = 0, cnt2 = 0, cnt3 = 0;

    unsigned long long MJ[4];               // composed j-match masks, current row
    unsigned long long Mi_prev[4];          // i-match masks of previous row
    unsigned long long MJL_prev[4];         // left-shifted j-masks of previous row
    float vc[4], vn[4];

    auto bperm64 = [&](unsigned long long v) -> unsigned long long {
        const unsigned int lo =
            (unsigned int)__builtin_amdgcn_ds_bpermute(baddr, (int)(unsigned int)v);
        const unsigned int hi =
            (unsigned int)__builtin_amdgcn_ds_bpermute(baddr, (int)(unsigned int)(v >> 32));
        return ((unsigned long long)hi << 32) | lo;
    };
    auto make_mj = [&]() {
        #pragma unroll
        for (int s = 0; s < 4; ++s) {
            const int q = (int)(vc[s] * 7.0f);
            const unsigned long long b0 = __ballot(q & 1);
            const unsigned long long b1 = __ballot(q & 2);
            const unsigned long long b2 = __ballot(q & 4);
            MJ[s] = (b0 ^ F0) & (b1 ^ F1) & (b2 ^ F2);
        }
    };

    // ---- prologue: row r0 (cnt0 of row y is deferred to iteration y+1) ----
    #pragma unroll
    for (int s = 0; s < 4; ++s) vc[s] = img[r0 * Wd + (s << 6) + lane];
    #pragma unroll
    for (int s = 0; s < 4; ++s) vn[s] = img[(r0 + 1) * Wd + (s << 6) + lane];
    make_mj();
    #pragma unroll
    for (int s = 0; s < 4; ++s) {
        MJL_prev[s] = (MJ[s] << 1) | (s ? (MJ[s - 1] >> 63) : JL0);
        Mi_prev[s] = bperm64(MJ[s]);
    }

    // ---- rows r0+1 .. r0+15 ----
    for (int yy = 1; yy < 16; ++yy) {
        #pragma unroll
        for (int s = 0; s < 4; ++s) vc[s] = vn[s];
        const int yn = r0 + yy + 1;
        if (yn < Hd) {                      // wave-uniform guard (last wave, yy==15)
            #pragma unroll
            for (int s = 0; s < 4; ++s) vn[s] = img[yn * Wd + (s << 6) + lane];
        }
        make_mj();
        #pragma unroll
        for (int s = 0; s < 4; ++s) {
            const unsigned long long mjl = (MJ[s] << 1) | (s ? (MJ[s - 1] >> 63) : JL0);
            const unsigned long long mjr = (MJ[s] >> 1) | (s < 3 ? (MJ[s + 1] << 63) : JR0);
            cnt0 += __popcll(Mi_prev[s] & MJL_prev[s]);   // angle0 of row yy-1
            cnt1 += __popcll(Mi_prev[s] & mjl);
            cnt2 += __popcll(Mi_prev[s] & MJ[s]);
            cnt3 += __popcll(Mi_prev[s] & mjr);
            MJL_prev[s] = mjl;
        }
        #pragma unroll
        for (int s = 0; s < 4; ++s) Mi_prev[s] = bperm64(MJ[s]);
    }

    // ---- boundary row r0+16 (next wave's first row, or zero pad) ----
    if (r0 + 16 < Hd) {
        #pragma unroll
        for (int s = 0; s < 4; ++s) vc[s] = vn[s];
        make_mj();
    } else {
        #pragma unroll
        for (int s = 0; s < 4; ++s) MJ[s] = MJPAD;
    }
    #pragma unroll
    for (int s = 0; s < 4; ++s) {
        const unsigned long long mjl = (MJ[s] << 1) | (s ? (MJ[s - 1] >> 63) : JL0);
        const unsigned long long mjr = (MJ[s] >> 1) | (s < 3 ? (MJ[s + 1] << 63) : JR0);
        cnt0 += __popcll(Mi_prev[s] & MJL_prev[s]);       // angle0 of row r0+15
        cnt1 += __popcll(Mi_prev[s] & mjl);
        cnt2 += __popcll(Mi_prev[s] & MJ[s]);
        cnt3 += __popcll(Mi_prev[s] & mjr);
    }

    __syncthreads();                        // hist init visible
    atomicAdd(&hist[  0 + lane], cnt0);
    atomicAdd(&hist[ 64 + lane], cnt1);
    atomicAdd(&hist[128 + lane], cnt2);
    atomicAdd(&hist[192 + lane], cnt3);
    __syncthreads();

    // ---- features: wave a (t<256) handles angle a; 64 bins = 64 lanes ----
    if (t < 256) {
        float csum, hsum, esum, rsum;
        {
            const int a = t >> 6;
            const int bin = t & 63;
            const float p = (float)hist[a * 64 + bin] * (1.0f / 65536.0f);
            const int i = bin >> 3, j = bin & 7;
            const int dij = i - j;
            const int adij = dij < 0 ? -dij : dij;
            csum = (float)(dij * dij) * p;
            hsum = p / (float)(1 + adij);
            esum = p * p;
            rsum = ((float)i - 3.5f) * ((float)j - 3.5f) * p;
        }
        #pragma unroll
        for (int m = 1; m < 64; m <<= 1) {
            csum += __shfl_xor(csum, m, 64);
            hsum += __shfl_xor(hsum, m, 64);
            esum += __shfl_xor(esum, m, 64);
            rsum += __shfl_xor(rsum, m, 64);
        }
        if ((t & 63) == 0) {
            const int a = t >> 6;
            feats_s[a * 4 + 0] = csum;
            feats_s[a * 4 + 1] = hsum;
            feats_s[a * 4 + 2] = esum;
            // I_STD^2 + 1e-6, I_STD = sqrt(6) (ddof=1 std of arange(8))
            feats_s[a * 4 + 3] = rsum * (1.0f / 6.000001f);
        }
    }
    __syncthreads();

    // ---- MLP: h = relu(feats @ W1); z = h @ W2[:, c]; w = sigmoid(z) ----
    if (t < 16) {
        float acc = 0.0f;
        #pragma unroll
        for (int f = 0; f < 16; ++f) acc += feats_s[f] * W1[f * 16 + t];
        h_s[t] = acc > 0.0f ? acc : 0.0f;
    }
    __syncthreads();
    if (t == 0) {
        const int c = bc & 63;
        float z = 0.0f;
        #pragma unroll
        for (int k = 0; k < 16; ++k) z += h_s[k] * W2[k * 64 + c];
        wplus_s = 1.0f + 1.0f / (1.0f + expf(-z));
    }
    __syncthreads();

    // ---- fused scale: out = x * wplus. Image re-read is L3-resident. ----
    const float w = wplus_s;
    const fvec4* img4 = (const fvec4*)img;
    fvec4* out4 = (fvec4*)(out + (size_t)bc * HW);
    #pragma unroll
    for (int k = 0; k < 16; ++k) {
        fvec4 p = img4[k * 1024 + t];
        p *= w;
        __builtin_nontemporal_store(p, &out4[k * 1024 + t]);
    }
}

extern "C" void kernel_launch(void* const* d_in, const int* in_sizes, int n_in,
                              void* d_out, int out_size, void* d_ws, size_t ws_size,
                              hipStream_t stream) {
    (void)in_sizes; (void)n_in; (void)d_ws; (void)ws_size; (void)out_size;
    const float* x  = (const float*)d_in[0];
    const float* W1 = (const float*)d_in[1];   // (16,16) row-major
    const float* W2 = (const float*)d_in[2];   // (16,64) row-major
    float* out = (float*)d_out;

    glcm_fused<<<512, 1024, 0, stream>>>(x, W1, W2, out);
}